// Round 1
// 22.081 us; speedup vs baseline: 1.4717x; 1.4717x over previous
//
#include <hip/hip_runtime.h>

#define SCALE 28.853900817779268f   // 20*log2(e): sigmoid(20(pk-pj)) = 1/(1+2^{SCALE*pj}*2^{-SCALE*pk})
#define M 2048                      // histogram bins over p in [0,1]
#define T 1024                      // threads per block
#define CPC 32                      // chunks (blocks) per class
#define QB (M/CPC)                  // 64 mk-bins handled per block

__device__ __forceinline__ float fexp2(float x){ return __builtin_amdgcn_exp2f(x); }
__device__ __forceinline__ float frcp (float x){ return __builtin_amdgcn_rcpf(x); }

#define WRED64(x) { _Pragma("unroll") for (int _o = 32; _o; _o >>= 1) x += __shfl_down(x, _o, 64); }

// Single fused kernel: 256 blocks = 8 classes x 32 chunks. Each block
// REDUNDANTLY builds the full class-c histogram in LDS (int atomics ->
// bit-identical across all 32 blocks of a class; same per-thread work as the
// old K1, since stride is 1024 either way), then computes its 64-mk-bin slice
// of the pair sum directly from its own LDS. This removes the 2nd kernel
// launch + inter-kernel gap that dominated the 32.5us (GPU work is only ~5us).
// Mod-NB persistent ticket (ONE fence, tid==0) elects last block to finalize.
__global__ __launch_bounds__(1024)
void k_fused(const float* __restrict__ logits, const int* __restrict__ tgt,
             float* __restrict__ out, unsigned int* __restrict__ ticket,
             float* __restrict__ gpart, int* __restrict__ ccnt, int N){
  const int b = blockIdx.x, NB = (int)gridDim.x;
  const int c = b >> 5, ch = b & (CPC-1);
  const int tid = threadIdx.x, lane = tid & 63, w = tid >> 6;
  const float invM = 1.0f / (float)M;

  __shared__ int   H[M], P[M];
  __shared__ float Bq[QB];
  __shared__ int   wnp[16];
  __shared__ float rw[16];
  __shared__ float scs[8];
  __shared__ int   lastflag;

  #pragma unroll
  for (int m = tid; m < M; m += T){ H[m] = 0; P[m] = 0; }
  __syncthreads();

  // ---- phase 1: class-c probability histogram over all rows (math identical
  // ---- to the verified K1: same expf chain, precise division, same binning)
  const float4* l4 = (const float4*)logits;
  for (int i = tid; i < N; i += T){
    float4 A = l4[2*i], B4 = l4[2*i+1];
    float x0=A.x,x1=A.y,x2=A.z,x3=A.w,x4=B4.x,x5=B4.y,x6=B4.z,x7=B4.w;
    float mx = fmaxf(fmaxf(fmaxf(x0,x1),fmaxf(x2,x3)),
                     fmaxf(fmaxf(x4,x5),fmaxf(x6,x7)));
    float e0=__expf(x0-mx), e1=__expf(x1-mx), e2=__expf(x2-mx), e3=__expf(x3-mx);
    float e4=__expf(x4-mx), e5=__expf(x5-mx), e6=__expf(x6-mx), e7=__expf(x7-mx);
    float s = ((e0+e1)+(e2+e3))+((e4+e5)+(e6+e7));
    float ec = e0;                        // static select of class-c exponent
    ec = (c==1)? e1 : ec;  ec = (c==2)? e2 : ec;  ec = (c==3)? e3 : ec;
    ec = (c==4)? e4 : ec;  ec = (c==5)? e5 : ec;  ec = (c==6)? e6 : ec;
    ec = (c==7)? e7 : ec;
    float p = ec / s;
    int bin = min((int)(p * (float)M), M-1);
    atomicAdd(&H[bin], 1);
    if (tgt[i] == c) atomicAdd(&P[bin], 1);
  }
  __syncthreads();

  // ---- fragment setup: per thread 2 (Ej,Hj) pairs + np partial ----
  float Ej0, Ej1, Hj0, Hj1; int np_part;
  {
    const int mj0 = tid, mj1 = tid + T;
    const int p0 = P[mj0], p1 = P[mj1];
    np_part = p0 + p1;
    Hj0 = (float)(H[mj0] - p0);
    Hj1 = (float)(H[mj1] - p1);
    Ej0 = fexp2(-SCALE * ((float)mj0 + 0.5f) * invM);
    Ej1 = fexp2(-SCALE * ((float)mj1 + 0.5f) * invM);
  }
  if (tid < QB)                           // hoist the 64 Bk transcendentals
    Bq[tid] = fexp2(SCALE * ((float)(ch*QB + tid) + 0.5f) * invM);
  WRED64(np_part)
  if (lane == 0) wnp[w] = np_part;
  __syncthreads();                        // Bq + wnp visible

  // ---- phase 2: pair partial over this block's 64 mk-bins ----
  float tot = 0.f;
  #pragma unroll 8
  for (int q = 0; q < QB; ++q){
    float Bk = Bq[q];                     // LDS uniform broadcast
    float Pk = (float)P[ch*QB + q];       // LDS uniform broadcast
    float s0 = Hj0 * frcp(fmaf(Bk, Ej0, 1.0f));
    float s1 = Hj1 * frcp(fmaf(Bk, Ej1, 1.0f));
    tot += Pk * (s0 + s1);
  }
  WRED64(tot)
  if (lane == 0) rw[w] = tot;
  __syncthreads();
  if (tid == 0){
    float bt = 0.f;
    #pragma unroll
    for (int i = 0; i < 16; ++i) bt += rw[i];
    atomicExch(&gpart[b], bt);            // coherent-point store (release data)
    if (ch == 0){                         // one writer/class; value identical in all
      int snp = 0;
      #pragma unroll
      for (int i = 0; i < 16; ++i) snp += wnp[i];
      atomicExch(&ccnt[c], snp);
    }
    __threadfence();                      // ONE fence per block (release)
    unsigned old = atomicAdd(ticket, 1u); // persistent; +NB per launch
    lastflag = ((old % (unsigned)NB) == (unsigned)(NB - 1));
  }
  __syncthreads();
  if (!lastflag) return;

  // ---- finalize (last block; fixed order -> deterministic) ----
  if (tid == 0) __threadfence();          // acquire
  __syncthreads();
  if (tid < 256){
    int c2 = tid >> 5, l = tid & 31;      // 8 classes x 32 chunks
    float s = atomicAdd(&gpart[c2*CPC + l], 0.0f);   // coherent read
    #pragma unroll
    for (int o = 16; o; o >>= 1) s += __shfl_down(s, o, 32);
    if (l == 0) scs[c2] = s;
  }
  __syncthreads();
  if (tid == 0){
    float total = 0.f, vc = 0.f;
    #pragma unroll
    for (int cc = 0; cc < 8; ++cc){
      int np = atomicAdd(&ccnt[cc], 0);   // coherent read
      int nn = N - np;
      if (np > 0 && nn > 0){
        total += scs[cc] / ((float)np * (float)nn);
        vc += 1.0f;
      }
    }
    out[0] = (vc > 0.f) ? (1.0f - total / vc) : 0.0f;
  }
}

extern "C" void kernel_launch(void* const* d_in, const int* in_sizes, int n_in,
                              void* d_out, int out_size, void* d_ws, size_t ws_size,
                              hipStream_t stream) {
    const float* logits = (const float*)d_in[0];
    const int*   tgt    = (const int*)d_in[1];
    float* out = (float*)d_out;
    int N = in_sizes[1];

    unsigned int* ticket = (unsigned int*)d_ws;        // persistent mod-NB ticket
    float* gpart = (float*)d_ws + 16;                  // 256 block partials
    int*   ccnt  = (int*)(gpart + 256);                // 8 positive counts

    k_fused<<<8*CPC, T, 0, stream>>>(logits, tgt, out, ticket, gpart, ccnt, N);
}

// Round 2
// 20.477 us; speedup vs baseline: 1.5870x; 1.0783x over previous
//
#include <hip/hip_runtime.h>

#define SCALE 28.853900817779268f   // 20*log2(e): sigmoid(20(pk-pj)) = 1/(1+2^{SCALE*pj}*2^{-SCALE*pk})
#define M 2048                      // histogram bins over p in [0,1]
#define T 1024                      // threads per block
#define CPC 32                      // chunks (blocks) per class
#define QB (M/CPC)                  // 64 mk-bins handled per block

__device__ __forceinline__ float fexp2(float x){ return __builtin_amdgcn_exp2f(x); }
__device__ __forceinline__ float frcp (float x){ return __builtin_amdgcn_rcpf(x); }

#define WRED64(x) { _Pragma("unroll") for (int _o = 32; _o; _o >>= 1) x += __shfl_down(x, _o, 64); }

// Single fused kernel: 256 blocks = 8 classes x 32 chunks. Each block
// REDUNDANTLY builds the full class-c histogram in LDS, then computes its
// 64-mk-bin slice of the pair sum from its own LDS. One dispatch total.
// This round: packed H/P into ONE int atomic (16:16), hoisted setup
// transcendentals ahead of phase 1, one barrier removed, rcp-based softmax
// divide, lane-parallel finalize. Integer histogram -> bit-deterministic.
__global__ __launch_bounds__(1024)
void k_fused(const float* __restrict__ logits, const int* __restrict__ tgt,
             float* __restrict__ out, unsigned int* __restrict__ ticket,
             float* __restrict__ gpart, int* __restrict__ ccnt, int N){
  const int b = blockIdx.x, NB = (int)gridDim.x;
  const int c = b >> 5, ch = b & (CPC-1);
  const int tid = threadIdx.x, lane = tid & 63, w = tid >> 6;
  const float invM = 1.0f / (float)M;

  __shared__ int   HP[M];            // low16 = all-rows count, high16 = positives
  __shared__ float Bq[QB];
  __shared__ int   wnp[16];
  __shared__ float rw[16];
  __shared__ float scs[8];
  __shared__ int   lastflag;

  // setup (no LDS deps yet): zero histogram, hoist all transcendental tables
  ((int2*)HP)[tid] = make_int2(0, 0);
  float Ej0 = fexp2(-SCALE * ((float)tid          + 0.5f) * invM);
  float Ej1 = fexp2(-SCALE * ((float)(tid + T)    + 0.5f) * invM);
  if (tid < QB)
    Bq[tid] = fexp2(SCALE * ((float)(ch*QB + tid) + 0.5f) * invM);
  __syncthreads();

  // ---- phase 1: class-c probability histogram over all rows ----
  const float4* l4 = (const float4*)logits;
  for (int i = tid; i < N; i += T){
    float4 A = l4[2*i], B4 = l4[2*i+1];
    float x0=A.x,x1=A.y,x2=A.z,x3=A.w,x4=B4.x,x5=B4.y,x6=B4.z,x7=B4.w;
    float mx = fmaxf(fmaxf(fmaxf(x0,x1),fmaxf(x2,x3)),
                     fmaxf(fmaxf(x4,x5),fmaxf(x6,x7)));
    float e0=__expf(x0-mx), e1=__expf(x1-mx), e2=__expf(x2-mx), e3=__expf(x3-mx);
    float e4=__expf(x4-mx), e5=__expf(x5-mx), e6=__expf(x6-mx), e7=__expf(x7-mx);
    float s = ((e0+e1)+(e2+e3))+((e4+e5)+(e6+e7));
    float ec = e0;                        // static select of class-c exponent
    ec = (c==1)? e1 : ec;  ec = (c==2)? e2 : ec;  ec = (c==3)? e3 : ec;
    ec = (c==4)? e4 : ec;  ec = (c==5)? e5 : ec;  ec = (c==6)? e6 : ec;
    ec = (c==7)? e7 : ec;
    float p = ec * frcp(s);               // ~1ulp vs IEEE div; bins unaffected
    int bin = min((int)(p * (float)M), M-1);
    int inc = 1 + ((tgt[i] == c) ? (1 << 16) : 0);
    atomicAdd(&HP[bin], inc);             // ONE packed atomic per row
  }
  __syncthreads();

  // ---- fragment extraction: per thread 2 (Ej,Hj) pairs + np partial ----
  float Hj0, Hj1; int np_part;
  {
    const int hp0 = HP[tid], hp1 = HP[tid + T];
    const int p0 = hp0 >> 16, p1 = hp1 >> 16;
    np_part = p0 + p1;
    Hj0 = (float)((hp0 & 0xFFFF) - p0);
    Hj1 = (float)((hp1 & 0xFFFF) - p1);
  }
  WRED64(np_part)
  if (lane == 0) wnp[w] = np_part;

  // ---- phase 2: pair partial over this block's 64 mk-bins ----
  float tot = 0.f;
  #pragma unroll 8
  for (int q = 0; q < QB; ++q){
    float Bk = Bq[q];                        // LDS uniform broadcast
    float Pk = (float)(HP[ch*QB + q] >> 16); // LDS uniform broadcast
    float s0 = Hj0 * frcp(fmaf(Bk, Ej0, 1.0f));
    float s1 = Hj1 * frcp(fmaf(Bk, Ej1, 1.0f));
    tot += Pk * (s0 + s1);
  }
  WRED64(tot)
  if (lane == 0) rw[w] = tot;
  __syncthreads();                           // rw + wnp visible
  if (tid == 0){
    float bt = 0.f;
    #pragma unroll
    for (int i = 0; i < 16; ++i) bt += rw[i];
    atomicExch(&gpart[b], bt);            // coherent-point store (release data)
    if (ch == 0){                         // one writer/class; value identical in all
      int snp = 0;
      #pragma unroll
      for (int i = 0; i < 16; ++i) snp += wnp[i];
      atomicExch(&ccnt[c], snp);
    }
    __threadfence();                      // ONE fence per block (release)
    unsigned old = atomicAdd(ticket, 1u); // persistent; +NB per launch
    lastflag = ((old % (unsigned)NB) == (unsigned)(NB - 1));
  }
  __syncthreads();
  if (!lastflag) return;

  // ---- finalize (last block; fixed order -> deterministic) ----
  if (tid == 0) __threadfence();          // acquire
  __syncthreads();
  if (tid < 256){
    int c2 = tid >> 5, l = tid & 31;      // 8 classes x 32 chunks
    float s = atomicAdd(&gpart[c2*CPC + l], 0.0f);   // coherent read
    #pragma unroll
    for (int o = 16; o; o >>= 1) s += __shfl_down(s, o, 32);
    if (l == 0) scs[c2] = s;
  }
  __syncthreads();
  if (tid < 8){                           // lane-parallel class combine
    int np = atomicAdd(&ccnt[tid], 0);    // coherent read
    int nn = N - np;
    bool valid = (np > 0 && nn > 0);
    float t = valid ? scs[tid] / ((float)np * (float)nn) : 0.f;
    float f = valid ? 1.f : 0.f;
    #pragma unroll
    for (int o = 4; o; o >>= 1){
      t += __shfl_down(t, o, 8);
      f += __shfl_down(f, o, 8);
    }
    if (tid == 0) out[0] = (f > 0.f) ? (1.0f - t / f) : 0.0f;
  }
}

extern "C" void kernel_launch(void* const* d_in, const int* in_sizes, int n_in,
                              void* d_out, int out_size, void* d_ws, size_t ws_size,
                              hipStream_t stream) {
    const float* logits = (const float*)d_in[0];
    const int*   tgt    = (const int*)d_in[1];
    float* out = (float*)d_out;
    int N = in_sizes[1];

    unsigned int* ticket = (unsigned int*)d_ws;        // persistent mod-NB ticket
    float* gpart = (float*)d_ws + 16;                  // 256 block partials
    int*   ccnt  = (int*)(gpart + 256);                // 8 positive counts

    k_fused<<<8*CPC, T, 0, stream>>>(logits, tgt, out, ticket, gpart, ccnt, N);
}

// Round 3
// 18.706 us; speedup vs baseline: 1.7373x; 1.0947x over previous
//
#include <hip/hip_runtime.h>

#define SCALE 28.853900817779268f   // 20*log2(e): sigmoid(20(pk-pj)) = 1/(1+2^{SCALE*pj}*2^{-SCALE*pk})
#define L2E   1.4426950408889634f   // log2(e)
#define M 2048                      // histogram bins over p in [0,1]
#define T 1024                      // threads per block
#define CPC 32                      // chunks (blocks) per class
#define QB (M/CPC)                  // 64 mk-bins handled per block (STRIDED: mk = ch + CPC*q)

__device__ __forceinline__ float fexp2(float x){ return __builtin_amdgcn_exp2f(x); }
__device__ __forceinline__ float frcp (float x){ return __builtin_amdgcn_rcpf(x); }

#define WRED64(x) { _Pragma("unroll") for (int _o = 32; _o; _o >>= 1) x += __shfl_down(x, _o, 64); }

// Single fused kernel: 256 blocks = 8 classes x 32 chunks. Each block
// REDUNDANTLY builds the full class-c histogram in LDS (packed 16:16 int
// atomic -> bit-deterministic), then computes a STRIDED 64-mk-bin slice of
// the pair sum (mk = ch + 32*q, so zero-positive bins -- skippable, uniform
// branch -- spread evenly across blocks; contiguous chunks would leave the
// dense-p blocks with ~no skips and no critical-path win).
// Max-free softmax: logits ~ N(0,1) so p_c = 1/sum_j 2^{(x_j-x_c)*L2E} is
// overflow-safe; deletes fmax tree + exp-select + numerator mul.
// Mod-NB persistent ticket (ONE fence, tid==0) elects last block to finalize;
// gpart written with atomicExch (overwrite) -> safe under workspace re-poison.
__global__ __launch_bounds__(1024)
void k_fused(const float* __restrict__ logits, const int* __restrict__ tgt,
             float* __restrict__ out, unsigned int* __restrict__ ticket,
             float* __restrict__ gpart, int* __restrict__ ccnt, int N){
  const int b = blockIdx.x, NB = (int)gridDim.x;
  const int c = b >> 5, ch = b & (CPC-1);
  const int tid = threadIdx.x, lane = tid & 63, w = tid >> 6;
  const float invM = 1.0f / (float)M;

  __shared__ int   HP[M];            // low16 = all-rows count, high16 = positives
  __shared__ float Bq[QB];
  __shared__ int   wnp[16];
  __shared__ float rw[16];
  __shared__ float scs[8];
  __shared__ int   lastflag;

  // setup (no LDS deps yet): zero histogram, hoist all transcendental tables
  ((int2*)HP)[tid] = make_int2(0, 0);
  float Ej0 = fexp2(-SCALE * ((float)tid          + 0.5f) * invM);
  float Ej1 = fexp2(-SCALE * ((float)(tid + T)    + 0.5f) * invM);
  if (tid < QB)                      // strided bin table: mk = ch + CPC*q
    Bq[tid] = fexp2(SCALE * ((float)(ch + CPC*tid) + 0.5f) * invM);
  __syncthreads();

  // ---- phase 1: class-c probability histogram over all rows ----
  const float4* l4 = (const float4*)logits;
  for (int i = tid; i < N; i += T){
    float4 A = l4[2*i], B4 = l4[2*i+1];
    float y0=A.x *L2E, y1=A.y *L2E, y2=A.z *L2E, y3=A.w *L2E;
    float y4=B4.x*L2E, y5=B4.y*L2E, y6=B4.z*L2E, y7=B4.w*L2E;
    float yc = y0;                        // static select of class-c value
    yc=(c==1)?y1:yc; yc=(c==2)?y2:yc; yc=(c==3)?y3:yc;
    yc=(c==4)?y4:yc; yc=(c==5)?y5:yc; yc=(c==6)?y6:yc; yc=(c==7)?y7:yc;
    float s = ((fexp2(y0-yc)+fexp2(y1-yc)) + (fexp2(y2-yc)+fexp2(y3-yc)))
            + ((fexp2(y4-yc)+fexp2(y5-yc)) + (fexp2(y6-yc)+fexp2(y7-yc)));
    float p = frcp(s);                    // p_c = 1/sum; ~1ulp vs IEEE
    int bin = min((int)(p * (float)M), M-1);
    int inc = 1 + ((tgt[i] == c) ? (1 << 16) : 0);
    atomicAdd(&HP[bin], inc);             // ONE packed atomic per row
  }
  __syncthreads();

  // ---- fragment extraction: per thread 2 (Ej,Hj) pairs + np partial ----
  float Hj0, Hj1; int np_part;
  {
    const int hp0 = HP[tid], hp1 = HP[tid + T];
    const int p0 = hp0 >> 16, p1 = hp1 >> 16;
    np_part = p0 + p1;
    Hj0 = (float)((hp0 & 0xFFFF) - p0);
    Hj1 = (float)((hp1 & 0xFFFF) - p1);
  }
  WRED64(np_part)
  if (lane == 0) wnp[w] = np_part;

  // ---- phase 2: pair partial over this block's 64 STRIDED mk-bins ----
  float tot = 0.f;
  #pragma unroll 4
  for (int q = 0; q < QB; ++q){
    int Pki = HP[ch + CPC*q] >> 16;       // LDS uniform broadcast
    if (Pki == 0) continue;               // wave-uniform skip: zero contribution
    float Bk = Bq[q];
    float Pk = (float)Pki;
    float s0 = Hj0 * frcp(fmaf(Bk, Ej0, 1.0f));
    float s1 = Hj1 * frcp(fmaf(Bk, Ej1, 1.0f));
    tot += Pk * (s0 + s1);
  }
  WRED64(tot)
  if (lane == 0) rw[w] = tot;
  __syncthreads();                           // rw + wnp visible
  if (tid == 0){
    float bt = 0.f;
    #pragma unroll
    for (int i = 0; i < 16; ++i) bt += rw[i];
    atomicExch(&gpart[b], bt);            // coherent-point store (release data)
    if (ch == 0){                         // one writer/class; value identical in all
      int snp = 0;
      #pragma unroll
      for (int i = 0; i < 16; ++i) snp += wnp[i];
      atomicExch(&ccnt[c], snp);
    }
    __threadfence();                      // ONE fence per block (release)
    unsigned old = atomicAdd(ticket, 1u); // persistent; +NB per launch
    lastflag = ((old % (unsigned)NB) == (unsigned)(NB - 1));
  }
  __syncthreads();
  if (!lastflag) return;

  // ---- finalize (last block; fixed order -> deterministic) ----
  if (tid == 0) __threadfence();          // acquire
  __syncthreads();
  if (tid < 256){
    int c2 = tid >> 5, l = tid & 31;      // 8 classes x 32 chunks
    float s = atomicAdd(&gpart[c2*CPC + l], 0.0f);   // coherent read
    #pragma unroll
    for (int o = 16; o; o >>= 1) s += __shfl_down(s, o, 32);
    if (l == 0) scs[c2] = s;
  }
  __syncthreads();
  if (tid < 8){                           // lane-parallel class combine
    int np = atomicAdd(&ccnt[tid], 0);    // coherent read
    int nn = N - np;
    bool valid = (np > 0 && nn > 0);
    float t = valid ? scs[tid] / ((float)np * (float)nn) : 0.f;
    float f = valid ? 1.f : 0.f;
    #pragma unroll
    for (int o = 4; o; o >>= 1){
      t += __shfl_down(t, o, 8);
      f += __shfl_down(f, o, 8);
    }
    if (tid == 0) out[0] = (f > 0.f) ? (1.0f - t / f) : 0.0f;
  }
}

extern "C" void kernel_launch(void* const* d_in, const int* in_sizes, int n_in,
                              void* d_out, int out_size, void* d_ws, size_t ws_size,
                              hipStream_t stream) {
    const float* logits = (const float*)d_in[0];
    const int*   tgt    = (const int*)d_in[1];
    float* out = (float*)d_out;
    int N = in_sizes[1];

    unsigned int* ticket = (unsigned int*)d_ws;        // persistent mod-NB ticket
    float* gpart = (float*)d_ws + 16;                  // 256 block partials
    int*   ccnt  = (int*)(gpart + 256);                // 8 positive counts

    k_fused<<<8*CPC, T, 0, stream>>>(logits, tgt, out, ticket, gpart, ccnt, N);
}